// Round 1
// baseline (354.019 us; speedup 1.0000x reference)
//
#include <hip/hip_runtime.h>

typedef __bf16 bf16;
typedef __attribute__((ext_vector_type(8))) __bf16 bf16x8;
typedef __attribute__((ext_vector_type(4))) __bf16 bf16x4;
typedef __attribute__((ext_vector_type(4))) float f32x4;

#define MFMA16(A, B, C) __builtin_amdgcn_mfma_f32_16x16x32_bf16(A, B, C, 0, 0, 0)

static __device__ __forceinline__ void wave_lgkm_wait() {
  asm volatile("s_waitcnt lgkmcnt(0)" ::: "memory");
}

// ---------------------------------------------------------------------------
// k_prep: weight bf16 conversion, yu bilinear upsample, gating coefficients
// grid = 201 blocks x 256
// ---------------------------------------------------------------------------
__global__ __launch_bounds__(256) void k_prep(
    const float* __restrict__ y, const float* __restrict__ wy, const float* __restrict__ by,
    const float* __restrict__ wq, const float* __restrict__ bq,
    const float* __restrict__ wk, const float* __restrict__ bk,
    const float* __restrict__ wv,
    bf16* __restrict__ wq_bf, bf16* __restrict__ wk_bf, bf16* __restrict__ wv_bf,
    float* __restrict__ yu, float* __restrict__ aq, float* __restrict__ cq,
    float* __restrict__ ak, float* __restrict__ ck)
{
  int blk = blockIdx.x, t = threadIdx.x;
  if (blk < 192) {
    // convert wq|wk|wv (3 x 65536 floats) to bf16
    int idx4 = blk * 256 + t;       // 0..49151
    int fo = idx4 * 4;
    const float* src; bf16* dst; int off;
    if (fo < 65536)       { src = wq; dst = wq_bf; off = fo; }
    else if (fo < 131072) { src = wk; dst = wk_bf; off = fo - 65536; }
    else                  { src = wv; dst = wv_bf; off = fo - 131072; }
    float4 v = *(const float4*)(src + off);
    bf16x4 o;
    o[0] = (bf16)v.x; o[1] = (bf16)v.y; o[2] = (bf16)v.z; o[3] = (bf16)v.w;
    *(bf16x4*)(dst + off) = o;
  } else if (blk < 200) {
    // bilinear upsample y[b,1,24,24] -> yu[b,96,96], half-pixel, edge clamp
    int b = blk - 192;
    const float* yb = y + b * 576;
#pragma unroll 1
    for (int i = 0; i < 36; ++i) {
      int e = t + i * 256;          // 0..9215
      int oh = e / 96, ow = e % 96;
      float sh = oh * 0.25f - 0.375f;
      float sw = ow * 0.25f - 0.375f;
      int ih0 = (int)floorf(sh);
      int iw0 = (int)floorf(sw);
      float fh = sh - (float)ih0, fw = sw - (float)iw0;
      int ih0c = min(23, max(0, ih0)), ih1c = min(23, max(0, ih0 + 1));
      int iw0c = min(23, max(0, iw0)), iw1c = min(23, max(0, iw0 + 1));
      float v00 = yb[ih0c * 24 + iw0c], v01 = yb[ih0c * 24 + iw1c];
      float v10 = yb[ih1c * 24 + iw0c], v11 = yb[ih1c * 24 + iw1c];
      yu[b * 9216 + e] = (1.0f - fh) * ((1.0f - fw) * v00 + fw * v01)
                       + fh * ((1.0f - fw) * v10 + fw * v11);
    }
  } else {
    // gate coefficients: aq = wq*wy, cq = wq*by + bq (same for k)
    int o = t;
    float saq = 0.f, scq = 0.f, sak = 0.f, sck = 0.f;
#pragma unroll 1
    for (int c = 0; c < 256; ++c) {
      float wyc = wy[c], byc = by[c];
      float qv = wq[o * 256 + c], kv = wk[o * 256 + c];
      saq += qv * wyc; scq += qv * byc;
      sak += kv * wyc; sck += kv * byc;
    }
    aq[o] = saq; cq[o] = scq + bq[o];
    ak[o] = sak; ck[o] = sck + bk[o];
  }
}

// ---------------------------------------------------------------------------
// k_proj: per (b,h) row: Wq/Wk/Wv projections (MFMA bf16), gating, write
//   q_g[bh][o][w]  (A-layout for scores GEMM)
//   k_g[bh][d][w]  (B-layout [n=d][k=w] for scores GEMM)
//   v_t[bh][w][d]  (B-layout [n=w][k=d] for out GEMM)
// grid = pairs blocks x 256 (4 waves)
// ---------------------------------------------------------------------------
__global__ __launch_bounds__(256, 2) void k_proj(
    const float* __restrict__ x, const float* __restrict__ yu,
    const bf16* __restrict__ wq_bf, const bf16* __restrict__ wk_bf, const bf16* __restrict__ wv_bf,
    const float* __restrict__ bq, const float* __restrict__ bk, const float* __restrict__ bv,
    const float* __restrict__ aq, const float* __restrict__ cq,
    const float* __restrict__ ak, const float* __restrict__ ck,
    bf16* __restrict__ q_g, bf16* __restrict__ k_g, bf16* __restrict__ v_t,
    int bh_base)
{
  // xs: x_row as [w][c], pitch 264 (pad to break power-of-2 bank strides)
  __shared__ __align__(16) bf16 xs[96 * 264];          // 50688 B
  // stage: per-wave [16 o][104 w] transpose staging for q/k writeout
  __shared__ __align__(16) bf16 stage[4 * 16 * 104];   // 13312 B

  int pl = blockIdx.x;
  int bh = bh_base + pl;
  int b = bh / 96, h = bh % 96;
  int t = threadIdx.x;
  int wid = t >> 6, lane = t & 63;
  int l15 = lane & 15, g = lane >> 4;

  // ---- load x[b,:,h,:] -> xs[w][c] (bf16) ----
  {
    const float* xrow = x + (size_t)b * 2359296 + (size_t)h * 96;
#pragma unroll
    for (int i = 0; i < 24; ++i) {
      int e = i * 256 + t;
      int c = e / 24, w4 = e % 24;
      float4 v = *(const float4*)(xrow + (size_t)c * 9216 + w4 * 4);
      xs[(w4 * 4 + 0) * 264 + c] = (bf16)v.x;
      xs[(w4 * 4 + 1) * 264 + c] = (bf16)v.y;
      xs[(w4 * 4 + 2) * 264 + c] = (bf16)v.z;
      xs[(w4 * 4 + 3) * 264 + c] = (bf16)v.w;
    }
  }
  __syncthreads();

  // yu gate values for this row, indexed by w = mt*16 + g*4 + r
  float4 yv[6];
  {
    const float* yr = yu + (size_t)bh * 96;
#pragma unroll
    for (int mt = 0; mt < 6; ++mt)
      yv[mt] = *(const float4*)(yr + mt * 16 + g * 4);
  }

  bf16* stg = stage + wid * (16 * 104);

  // ---- q and k projections (swapped orientation: D[m=w][n=o]) ----
#pragma unroll 1
  for (int p = 0; p < 2; ++p) {
    const bf16* wb   = p ? wk_bf : wq_bf;
    const float* bias = p ? bk : bq;
    const float* av   = p ? ak : aq;
    const float* cv   = p ? ck : cq;
    bf16* dst = p ? k_g : q_g;

    f32x4 acc[6][4] = {};
#pragma unroll 1
    for (int ks = 0; ks < 8; ++ks) {
      bf16x8 A[6];
      const bf16* xp = xs + ks * 32 + g * 8;
#pragma unroll
      for (int m = 0; m < 6; ++m)
        A[m] = *(const bf16x8*)(xp + (m * 16 + l15) * 264);
      const bf16* wp = wb + (size_t)(wid * 64 + l15) * 256 + ks * 32 + g * 8;
#pragma unroll
      for (int n = 0; n < 4; ++n) {
        bf16x8 B = *(const bf16x8*)(wp + n * 16 * 256);
#pragma unroll
        for (int m = 0; m < 6; ++m)
          acc[m][n] = MFMA16(A[m], B, acc[m][n]);
      }
    }

    // gate + transpose-stage + coalesced writeout, one o-tile (16 rows) at a time
#pragma unroll 1
    for (int n = 0; n < 4; ++n) {
      int o = wid * 64 + n * 16 + l15;
      float biasv = bias[o], a0 = av[o], c0 = cv[o];
#pragma unroll
      for (int m = 0; m < 6; ++m) {
        float yy[4] = {yv[m].x, yv[m].y, yv[m].z, yv[m].w};
        bf16x4 pk;
#pragma unroll
        for (int r = 0; r < 4; ++r) {
          float val = (acc[m][n][r] + biasv) * (yy[r] * a0 + c0);
          pk[r] = (bf16)val;
        }
        // stage[o_local = l15][w = m*16 + g*4 .. +3]
        *(bf16x4*)(stg + l15 * 104 + m * 16 + g * 4) = pk;
      }
      wave_lgkm_wait();
      size_t gbase = (size_t)pl * 24576 + (size_t)(wid * 64 + n * 16) * 96;
#pragma unroll
      for (int cc = 0; cc < 3; ++cc) {
        int ch = lane + cc * 64;         // 0..191 chunks of 8 bf16
        int row = ch / 12, wc = ch % 12;
        bf16x8 v8 = *(const bf16x8*)(stg + row * 104 + wc * 8);
        *(bf16x8*)(dst + gbase + (size_t)row * 96 + wc * 8) = v8;
      }
      wave_lgkm_wait();
    }
  }

  // ---- v projection (natural orientation: D[m=d][n=w]) ----
  {
    f32x4 acc[4][6] = {};
#pragma unroll 1
    for (int ks = 0; ks < 8; ++ks) {
      bf16x8 A[4];
      const bf16* wp = wv_bf + (size_t)(wid * 64 + l15) * 256 + ks * 32 + g * 8;
#pragma unroll
      for (int m = 0; m < 4; ++m)
        A[m] = *(const bf16x8*)(wp + m * 16 * 256);
      const bf16* xp = xs + ks * 32 + g * 8;
#pragma unroll
      for (int n = 0; n < 6; ++n) {
        bf16x8 B = *(const bf16x8*)(xp + (n * 16 + l15) * 264);
#pragma unroll
        for (int m = 0; m < 4; ++m)
          acc[m][n] = MFMA16(A[m], B, acc[m][n]);
      }
    }
#pragma unroll
    for (int m = 0; m < 4; ++m) {
      int d0 = wid * 64 + m * 16 + g * 4;
      float4 bvv = *(const float4*)(bv + d0);
      float bb[4] = {bvv.x, bvv.y, bvv.z, bvv.w};
#pragma unroll
      for (int n = 0; n < 6; ++n) {
        int w = n * 16 + l15;
        bf16x4 pk;
#pragma unroll
        for (int r = 0; r < 4; ++r) pk[r] = (bf16)(acc[m][n][r] + bb[r]);
        // v_t[w][d0..d0+3] : 8B packed transposed store
        *(bf16x4*)(v_t + (size_t)pl * 24576 + (size_t)w * 256 + d0) = pk;
      }
    }
  }
}

// ---------------------------------------------------------------------------
// k_attn: per (b,h): scores = q k^T /sqrt(32), streaming softmax (no max
// subtraction: |scores| << 1 by construction), out = probs v, divide by sum.
// grid = pairs blocks x 256 (4 waves); wave owns 64 o-rows.
// ---------------------------------------------------------------------------
__global__ __launch_bounds__(256, 2) void k_attn(
    const bf16* __restrict__ q_g, const bf16* __restrict__ k_g, const bf16* __restrict__ v_t,
    float* __restrict__ out, int bh_base)
{
  // per-wave D-layout -> A-layout bounce, [64 o][40 d] (pitch 40 vs 32: conflicts)
  __shared__ __align__(16) bf16 bounce[4 * 64 * 40];   // 20480 B

  int pl = blockIdx.x;
  int bh = bh_base + pl;
  int b = bh / 96, h = bh % 96;
  int t = threadIdx.x;
  int wid = t >> 6, lane = t & 63;
  int l15 = lane & 15, g = lane >> 4;

  // q A-fragments for this wave's 64 o-rows (held in registers)
  bf16x8 qf[4][3];
  {
    const bf16* qp = q_g + (size_t)pl * 24576 + (size_t)(wid * 64 + l15) * 96 + g * 8;
#pragma unroll
    for (int m = 0; m < 4; ++m)
#pragma unroll
      for (int kk = 0; kk < 3; ++kk)
        qf[m][kk] = *(const bf16x8*)(qp + m * 16 * 96 + kk * 32);
  }

  f32x4 oacc[4][6] = {};
  float lp[4][4];
#pragma unroll
  for (int m = 0; m < 4; ++m)
#pragma unroll
    for (int r = 0; r < 4; ++r) lp[m][r] = 0.0f;

  bf16* bnc = bounce + wid * (64 * 40);
  const float SC = 0.17677669529663687f;   // 1/sqrt(32)

#pragma unroll 1
  for (int dt = 0; dt < 8; ++dt) {
    int d0 = dt * 32;
    f32x4 s[4][2] = {};
    const bf16* kp = k_g + (size_t)pl * 24576 + (size_t)(d0 + l15) * 96 + g * 8;
#pragma unroll
    for (int kk = 0; kk < 3; ++kk) {
#pragma unroll
      for (int dn = 0; dn < 2; ++dn) {
        bf16x8 B = *(const bf16x8*)(kp + (size_t)dn * 16 * 96 + kk * 32);
#pragma unroll
        for (int m = 0; m < 4; ++m)
          s[m][dn] = MFMA16(qf[m][kk], B, s[m][dn]);
      }
    }
    // exp (scores are tiny: no max subtraction needed), accumulate row sums,
    // bounce through LDS to A-layout
#pragma unroll
    for (int m = 0; m < 4; ++m) {
#pragma unroll
      for (int dn = 0; dn < 2; ++dn) {
#pragma unroll
        for (int r = 0; r < 4; ++r) {
          float e = __expf(s[m][dn][r] * SC);
          lp[m][r] += e;
          bnc[(m * 16 + g * 4 + r) * 40 + dn * 16 + l15] = (bf16)e;
        }
      }
    }
    wave_lgkm_wait();
    bf16x8 pa[4];
#pragma unroll
    for (int m = 0; m < 4; ++m)
      pa[m] = *(const bf16x8*)(bnc + (m * 16 + l15) * 40 + g * 8);
    const bf16* vp = v_t + (size_t)pl * 24576 + (size_t)l15 * 256 + d0 + g * 8;
#pragma unroll
    for (int n = 0; n < 6; ++n) {
      bf16x8 Bv = *(const bf16x8*)(vp + (size_t)n * 16 * 256);
#pragma unroll
      for (int m = 0; m < 4; ++m)
        oacc[m][n] = MFMA16(pa[m], Bv, oacc[m][n]);
    }
    wave_lgkm_wait();   // pa reads retired before next-iter bounce writes (per-wave WAR)
  }

  // reduce row sums across the 16 lanes holding the same rows
#pragma unroll
  for (int m = 0; m < 4; ++m)
#pragma unroll
    for (int r = 0; r < 4; ++r) {
      float v = lp[m][r];
      v += __shfl_xor(v, 1, 16);
      v += __shfl_xor(v, 2, 16);
      v += __shfl_xor(v, 4, 16);
      v += __shfl_xor(v, 8, 16);
      lp[m][r] = 1.0f / v;
    }

  // epilogue: out[b, o, h, w] = oacc / rowsum
  float* ob = out + (size_t)b * 2359296 + (size_t)h * 96;
#pragma unroll
  for (int m = 0; m < 4; ++m) {
    int obase = wid * 64 + m * 16 + g * 4;
#pragma unroll
    for (int r = 0; r < 4; ++r) {
      float inv = lp[m][r];
      size_t rowoff = (size_t)(obase + r) * 9216;
#pragma unroll
      for (int n = 0; n < 6; ++n)
        ob[rowoff + n * 16 + l15] = oacc[m][n][r] * inv;
    }
  }
}

// ---------------------------------------------------------------------------
extern "C" void kernel_launch(void* const* d_in, const int* in_sizes, int n_in,
                              void* d_out, int out_size, void* d_ws, size_t ws_size,
                              hipStream_t stream) {
  const float* x  = (const float*)d_in[0];
  const float* y  = (const float*)d_in[1];
  const float* wy = (const float*)d_in[2];
  const float* by = (const float*)d_in[3];
  const float* wq = (const float*)d_in[4];
  const float* bq = (const float*)d_in[5];
  const float* wk = (const float*)d_in[6];
  const float* bk = (const float*)d_in[7];
  const float* wv = (const float*)d_in[8];
  const float* bv = (const float*)d_in[9];
  float* out = (float*)d_out;

  char* wsb = (char*)d_ws;
  bf16* wq_bf = (bf16*)(wsb);
  bf16* wk_bf = (bf16*)(wsb + 131072);
  bf16* wv_bf = (bf16*)(wsb + 262144);
  float* yu   = (float*)(wsb + 393216);
  float* aq   = (float*)(wsb + 688128);
  float* cq   = (float*)(wsb + 689152);
  float* ak   = (float*)(wsb + 690176);
  float* ck   = (float*)(wsb + 691200);
  const size_t fixed = 692224;
  const size_t per_bh = 3 * 24576 * 2;   // q,k,v bf16 per (b,h) pair

  // chunk over batch so any reasonable ws_size works (>= ~15 MB -> 1 batch/chunk)
  size_t avail = ws_size > fixed ? ws_size - fixed : 0;
  long cap = (long)(avail / per_bh);
  int nb = (int)(cap / 96);
  if (nb > 8) nb = 8;
  if (nb < 1) nb = 1;
  int chunk_pairs = nb * 96;

  bf16* q_g = (bf16*)(wsb + fixed);
  bf16* k_g = q_g + (size_t)chunk_pairs * 24576;
  bf16* v_t = k_g + (size_t)chunk_pairs * 24576;

  hipLaunchKernelGGL(k_prep, dim3(201), dim3(256), 0, stream,
                     y, wy, by, wq, bq, wk, bk, wv,
                     wq_bf, wk_bf, wv_bf, yu, aq, cq, ak, ck);
  for (int b0 = 0; b0 < 8; b0 += nb) {
    int nbc = nb; if (b0 + nbc > 8) nbc = 8 - b0;
    int pairs = nbc * 96;
    hipLaunchKernelGGL(k_proj, dim3(pairs), dim3(256), 0, stream,
                       x, yu, wq_bf, wk_bf, wv_bf, bq, bk, bv,
                       aq, cq, ak, ck, q_g, k_g, v_t, b0 * 96);
    hipLaunchKernelGGL(k_attn, dim3(pairs), dim3(256), 0, stream,
                       q_g, k_g, v_t, out, b0 * 96);
  }
}

// Round 2
// 331.893 us; speedup vs baseline: 1.0667x; 1.0667x over previous
//
#include <hip/hip_runtime.h>

typedef __bf16 bf16;
typedef __attribute__((ext_vector_type(8))) __bf16 bf16x8;
typedef __attribute__((ext_vector_type(4))) __bf16 bf16x4;
typedef __attribute__((ext_vector_type(4))) float f32x4;

#define MFMA16(A, B, C) __builtin_amdgcn_mfma_f32_16x16x32_bf16(A, B, C, 0, 0, 0)

static __device__ __forceinline__ void wave_lgkm_wait() {
  asm volatile("s_waitcnt lgkmcnt(0)" ::: "memory");
}

// ---------------------------------------------------------------------------
// k_prep: weight bf16 conversion, yu bilinear upsample, gating coefficients
// grid = 232 blocks x 256
// ---------------------------------------------------------------------------
__global__ __launch_bounds__(256) void k_prep(
    const float* __restrict__ y, const float* __restrict__ wy, const float* __restrict__ by,
    const float* __restrict__ wq, const float* __restrict__ bq,
    const float* __restrict__ wk, const float* __restrict__ bk,
    const float* __restrict__ wv,
    bf16* __restrict__ wq_bf, bf16* __restrict__ wk_bf, bf16* __restrict__ wv_bf,
    float* __restrict__ yu, float* __restrict__ aq, float* __restrict__ cq,
    float* __restrict__ ak, float* __restrict__ ck)
{
  int blk = blockIdx.x, t = threadIdx.x;
  if (blk < 192) {
    // convert wq|wk|wv (3 x 65536 floats) to bf16
    int idx4 = blk * 256 + t;       // 0..49151
    int fo = idx4 * 4;
    const float* src; bf16* dst; int off;
    if (fo < 65536)       { src = wq; dst = wq_bf; off = fo; }
    else if (fo < 131072) { src = wk; dst = wk_bf; off = fo - 65536; }
    else                  { src = wv; dst = wv_bf; off = fo - 131072; }
    float4 v = *(const float4*)(src + off);
    bf16x4 o;
    o[0] = (bf16)v.x; o[1] = (bf16)v.y; o[2] = (bf16)v.z; o[3] = (bf16)v.w;
    *(bf16x4*)(dst + off) = o;
  } else if (blk < 200) {
    // bilinear upsample y[b,1,24,24] -> yu[b,96,96], half-pixel, edge clamp
    int b = blk - 192;
    const float* yb = y + b * 576;
#pragma unroll 1
    for (int i = 0; i < 36; ++i) {
      int e = t + i * 256;          // 0..9215
      int oh = e / 96, ow = e % 96;
      float sh = oh * 0.25f - 0.375f;
      float sw = ow * 0.25f - 0.375f;
      int ih0 = (int)floorf(sh);
      int iw0 = (int)floorf(sw);
      float fh = sh - (float)ih0, fw = sw - (float)iw0;
      int ih0c = min(23, max(0, ih0)), ih1c = min(23, max(0, ih0 + 1));
      int iw0c = min(23, max(0, iw0)), iw1c = min(23, max(0, iw0 + 1));
      float v00 = yb[ih0c * 24 + iw0c], v01 = yb[ih0c * 24 + iw1c];
      float v10 = yb[ih1c * 24 + iw0c], v11 = yb[ih1c * 24 + iw1c];
      yu[b * 9216 + e] = (1.0f - fh) * ((1.0f - fw) * v00 + fw * v01)
                       + fh * ((1.0f - fw) * v10 + fw * v11);
    }
  } else {
    // gate coefficients: aq = wq*wy, cq = wq*by + bq (same for k)
    // 32 blocks x (8 o x 32 lanes); each lane owns 8 consecutive c
    int ol = t >> 5, cl = t & 31;
    int o = (blk - 200) * 8 + ol;
    int c0 = cl * 8;
    float4 wy0 = *(const float4*)(wy + c0), wy1 = *(const float4*)(wy + c0 + 4);
    float4 by0 = *(const float4*)(by + c0), by1 = *(const float4*)(by + c0 + 4);
    float4 q0  = *(const float4*)(wq + o * 256 + c0), q1 = *(const float4*)(wq + o * 256 + c0 + 4);
    float4 k0  = *(const float4*)(wk + o * 256 + c0), k1 = *(const float4*)(wk + o * 256 + c0 + 4);
    float wyv[8] = {wy0.x, wy0.y, wy0.z, wy0.w, wy1.x, wy1.y, wy1.z, wy1.w};
    float byv[8] = {by0.x, by0.y, by0.z, by0.w, by1.x, by1.y, by1.z, by1.w};
    float qv[8]  = {q0.x, q0.y, q0.z, q0.w, q1.x, q1.y, q1.z, q1.w};
    float kv[8]  = {k0.x, k0.y, k0.z, k0.w, k1.x, k1.y, k1.z, k1.w};
    float saq = 0.f, scq = 0.f, sak = 0.f, sck = 0.f;
#pragma unroll
    for (int j = 0; j < 8; ++j) {
      saq += qv[j] * wyv[j]; scq += qv[j] * byv[j];
      sak += kv[j] * wyv[j]; sck += kv[j] * byv[j];
    }
#pragma unroll
    for (int s = 16; s >= 1; s >>= 1) {
      saq += __shfl_xor(saq, s, 32);
      scq += __shfl_xor(scq, s, 32);
      sak += __shfl_xor(sak, s, 32);
      sck += __shfl_xor(sck, s, 32);
    }
    if (cl == 0) {
      aq[o] = saq; cq[o] = scq + bq[o];
      ak[o] = sak; ck[o] = sck + bk[o];
    }
  }
}

// ---------------------------------------------------------------------------
// k_proj: per (b,h) row: Wq/Wk/Wv projections (MFMA bf16), gating, write
//   q_g[bh][o][w]  (A-layout for scores GEMM)
//   k_g[bh][d][w]  (B-layout [n=d][k=w] for scores GEMM)
//   v_t[bh][w][d]  (B-layout [n=w][k=d] for out GEMM)
// grid = pairs blocks x 256 (4 waves)
// ---------------------------------------------------------------------------
__global__ __launch_bounds__(256, 2) void k_proj(
    const float* __restrict__ x, const float* __restrict__ yu,
    const bf16* __restrict__ wq_bf, const bf16* __restrict__ wk_bf, const bf16* __restrict__ wv_bf,
    const float* __restrict__ bq, const float* __restrict__ bk, const float* __restrict__ bv,
    const float* __restrict__ aq, const float* __restrict__ cq,
    const float* __restrict__ ak, const float* __restrict__ ck,
    bf16* __restrict__ q_g, bf16* __restrict__ k_g, bf16* __restrict__ v_t,
    int bh_base)
{
  // xs: x_row as [w][c], pitch 264 (b128 banks spread 4(w+cg)%32 = floor)
  __shared__ __align__(16) bf16 xs[96 * 264];          // 50688 B
  // stage: per-wave [16 o][104 w] for q/k writeout; reused as block-level
  // vstage [16 w][264 d] for the v writeout (8448 B <= 13312 B)
  __shared__ __align__(16) bf16 stage[4 * 16 * 104];   // 13312 B

  int pl = blockIdx.x;
  int bh = bh_base + pl;
  int b = bh / 96, h = bh % 96;
  int t = threadIdx.x;
  int wid = t >> 6, lane = t & 63;
  int l15 = lane & 15, g = lane >> 4;

  // ---- load x[b,:,h,:] -> xs[w][c] (bf16) ----
  // per task: one w, 8 consecutive c (8 coalesced scalar loads, one 16B LDS store)
  {
    const float* xrow = x + (size_t)b * 2359296 + (size_t)h * 96;
#pragma unroll 2
    for (int i = 0; i < 12; ++i) {
      int tsk = i * 256 + t;        // 0..3071 = 96 w x 32 cgroups
      int w = tsk % 96;
      int c0 = (tsk / 96) * 8;
      float v[8];
#pragma unroll
      for (int j = 0; j < 8; ++j) v[j] = xrow[(size_t)(c0 + j) * 9216 + w];
      bf16x8 o8;
#pragma unroll
      for (int j = 0; j < 8; ++j) o8[j] = (bf16)v[j];
      *(bf16x8*)(xs + w * 264 + c0) = o8;
    }
  }
  __syncthreads();

  // yu gate values for this row, indexed by w = mt*16 + g*4 + r
  float4 yv[6];
  {
    const float* yr = yu + (size_t)bh * 96;
#pragma unroll
    for (int mt = 0; mt < 6; ++mt)
      yv[mt] = *(const float4*)(yr + mt * 16 + g * 4);
  }

  bf16* stg = stage + wid * (16 * 104);

  // ---- q and k projections (swapped orientation: D[m=w][n=o]) ----
#pragma unroll 1
  for (int p = 0; p < 2; ++p) {
    const bf16* wb   = p ? wk_bf : wq_bf;
    const float* bias = p ? bk : bq;
    const float* av   = p ? ak : aq;
    const float* cv   = p ? ck : cq;
    bf16* dst = p ? k_g : q_g;

    f32x4 acc[6][4] = {};
#pragma unroll 1
    for (int ks = 0; ks < 8; ++ks) {
      bf16x8 A[6];
      const bf16* xp = xs + ks * 32 + g * 8;
#pragma unroll
      for (int m = 0; m < 6; ++m)
        A[m] = *(const bf16x8*)(xp + (m * 16 + l15) * 264);
      const bf16* wp = wb + (size_t)(wid * 64 + l15) * 256 + ks * 32 + g * 8;
#pragma unroll
      for (int n = 0; n < 4; ++n) {
        bf16x8 B = *(const bf16x8*)(wp + n * 16 * 256);
#pragma unroll
        for (int m = 0; m < 6; ++m)
          acc[m][n] = MFMA16(A[m], B, acc[m][n]);
      }
    }

    // gate + transpose-stage + coalesced writeout, one o-tile (16 rows) at a time
#pragma unroll 1
    for (int n = 0; n < 4; ++n) {
      int o = wid * 64 + n * 16 + l15;
      float biasv = bias[o], a0 = av[o], c0 = cv[o];
#pragma unroll
      for (int m = 0; m < 6; ++m) {
        float yy[4] = {yv[m].x, yv[m].y, yv[m].z, yv[m].w};
        bf16x4 pk;
#pragma unroll
        for (int r = 0; r < 4; ++r) {
          float val = (acc[m][n][r] + biasv) * (yy[r] * a0 + c0);
          pk[r] = (bf16)val;
        }
        // stage[o_local = l15][w = m*16 + g*4 .. +3]
        *(bf16x4*)(stg + l15 * 104 + m * 16 + g * 4) = pk;
      }
      wave_lgkm_wait();
      size_t gbase = (size_t)pl * 24576 + (size_t)(wid * 64 + n * 16) * 96;
#pragma unroll
      for (int cc = 0; cc < 3; ++cc) {
        int ch = lane + cc * 64;         // 0..191 chunks of 8 bf16
        int row = ch / 12, wc = ch % 12;
        bf16x8 v8 = *(const bf16x8*)(stg + row * 104 + wc * 8);
        *(bf16x8*)(dst + gbase + (size_t)row * 96 + wc * 8) = v8;
      }
      wave_lgkm_wait();
    }
  }

  // ---- v projection (natural orientation: D[m=d][n=w]) ----
  {
    f32x4 acc[4][6] = {};
#pragma unroll 1
    for (int ks = 0; ks < 8; ++ks) {
      bf16x8 A[4];
      const bf16* wp = wv_bf + (size_t)(wid * 64 + l15) * 256 + ks * 32 + g * 8;
#pragma unroll
      for (int m = 0; m < 4; ++m)
        A[m] = *(const bf16x8*)(wp + m * 16 * 256);
      const bf16* xp = xs + ks * 32 + g * 8;
#pragma unroll
      for (int n = 0; n < 6; ++n) {
        bf16x8 B = *(const bf16x8*)(xp + (n * 16 + l15) * 264);
#pragma unroll
        for (int m = 0; m < 4; ++m)
          acc[m][n] = MFMA16(A[m], B, acc[m][n]);
      }
    }

    // bias + block-level transpose staging per 16-w stripe, then full-line
    // global stores (v_t row = 512B; each stripe = 16 rows x 512B contiguous)
    float4 bvv = *(const float4*)(bv + wid * 64 + g * 4);   // m=0 tile
    float bb[4][4];
#pragma unroll
    for (int m = 0; m < 4; ++m) {
      float4 bm = *(const float4*)(bv + wid * 64 + m * 16 + g * 4);
      bb[m][0] = bm.x; bb[m][1] = bm.y; bb[m][2] = bm.z; bb[m][3] = bm.w;
    }
    (void)bvv;
    bf16* vst = stage;   // reuse: [16 w][264 d]
    __syncthreads();     // q/k stage use fully retired before overwrite
#pragma unroll 1
    for (int n = 0; n < 6; ++n) {
#pragma unroll
      for (int m = 0; m < 4; ++m) {
        int d0 = wid * 64 + m * 16 + g * 4;
        bf16x4 pk;
#pragma unroll
        for (int r = 0; r < 4; ++r) pk[r] = (bf16)(acc[m][n][r] + bb[m][r]);
        *(bf16x4*)(vst + l15 * 264 + d0) = pk;
      }
      __syncthreads();
      size_t gb = (size_t)pl * 24576 + (size_t)(n * 16) * 256;
#pragma unroll
      for (int rr = 0; rr < 2; ++rr) {
        int idx = rr * 256 + t;        // 0..511 chunks of 16B
        int row = idx >> 5, ch = idx & 31;
        bf16x8 v8 = *(const bf16x8*)(vst + row * 264 + ch * 8);
        *(bf16x8*)(v_t + gb + (size_t)row * 256 + ch * 8) = v8;
      }
      __syncthreads();
    }
  }
}

// ---------------------------------------------------------------------------
// k_attn: per (b,h): scores = q k^T /sqrt(32), streaming softmax (no max
// subtraction: |scores| << 1 by construction), out = probs v, divide by sum.
// grid = pairs blocks x 256 (4 waves); wave owns 64 o-rows.
// ---------------------------------------------------------------------------
__global__ __launch_bounds__(256, 2) void k_attn(
    const bf16* __restrict__ q_g, const bf16* __restrict__ k_g, const bf16* __restrict__ v_t,
    float* __restrict__ out, int bh_base)
{
  // per-wave D-layout -> A-layout bounce, [64 o][40 d] (pitch 40 vs 32: conflicts)
  __shared__ __align__(16) bf16 bounce[4 * 64 * 40];   // 20480 B

  int pl = blockIdx.x;
  int bh = bh_base + pl;
  int b = bh / 96, h = bh % 96;
  int t = threadIdx.x;
  int wid = t >> 6, lane = t & 63;
  int l15 = lane & 15, g = lane >> 4;

  // q A-fragments for this wave's 64 o-rows (held in registers)
  bf16x8 qf[4][3];
  {
    const bf16* qp = q_g + (size_t)pl * 24576 + (size_t)(wid * 64 + l15) * 96 + g * 8;
#pragma unroll
    for (int m = 0; m < 4; ++m)
#pragma unroll
      for (int kk = 0; kk < 3; ++kk)
        qf[m][kk] = *(const bf16x8*)(qp + m * 16 * 96 + kk * 32);
  }

  f32x4 oacc[4][6] = {};
  float lp[4][4];
#pragma unroll
  for (int m = 0; m < 4; ++m)
#pragma unroll
    for (int r = 0; r < 4; ++r) lp[m][r] = 0.0f;

  bf16* bnc = bounce + wid * (64 * 40);
  const float SC = 0.17677669529663687f;   // 1/sqrt(32)

#pragma unroll 1
  for (int dt = 0; dt < 8; ++dt) {
    int d0 = dt * 32;
    f32x4 s[4][2] = {};
    const bf16* kp = k_g + (size_t)pl * 24576 + (size_t)(d0 + l15) * 96 + g * 8;
#pragma unroll
    for (int kk = 0; kk < 3; ++kk) {
#pragma unroll
      for (int dn = 0; dn < 2; ++dn) {
        bf16x8 B = *(const bf16x8*)(kp + (size_t)dn * 16 * 96 + kk * 32);
#pragma unroll
        for (int m = 0; m < 4; ++m)
          s[m][dn] = MFMA16(qf[m][kk], B, s[m][dn]);
      }
    }
    // exp (scores are tiny: no max subtraction needed), accumulate row sums,
    // bounce through LDS to A-layout
#pragma unroll
    for (int m = 0; m < 4; ++m) {
#pragma unroll
      for (int dn = 0; dn < 2; ++dn) {
#pragma unroll
        for (int r = 0; r < 4; ++r) {
          float e = __expf(s[m][dn][r] * SC);
          lp[m][r] += e;
          bnc[(m * 16 + g * 4 + r) * 40 + dn * 16 + l15] = (bf16)e;
        }
      }
    }
    wave_lgkm_wait();
    bf16x8 pa[4];
#pragma unroll
    for (int m = 0; m < 4; ++m)
      pa[m] = *(const bf16x8*)(bnc + (m * 16 + l15) * 40 + g * 8);
    const bf16* vp = v_t + (size_t)pl * 24576 + (size_t)l15 * 256 + d0 + g * 8;
#pragma unroll
    for (int n = 0; n < 6; ++n) {
      bf16x8 Bv = *(const bf16x8*)(vp + (size_t)n * 16 * 256);
#pragma unroll
      for (int m = 0; m < 4; ++m)
        oacc[m][n] = MFMA16(pa[m], Bv, oacc[m][n]);
    }
    wave_lgkm_wait();   // pa reads retired before next-iter bounce writes (per-wave WAR)
  }

  // reduce row sums across the 16 lanes holding the same rows
#pragma unroll
  for (int m = 0; m < 4; ++m)
#pragma unroll
    for (int r = 0; r < 4; ++r) {
      float v = lp[m][r];
      v += __shfl_xor(v, 1, 16);
      v += __shfl_xor(v, 2, 16);
      v += __shfl_xor(v, 4, 16);
      v += __shfl_xor(v, 8, 16);
      lp[m][r] = 1.0f / v;
    }

  // epilogue: out[b, o, h, w] = oacc / rowsum
  float* ob = out + (size_t)b * 2359296 + (size_t)h * 96;
#pragma unroll
  for (int m = 0; m < 4; ++m) {
    int obase = wid * 64 + m * 16 + g * 4;
#pragma unroll
    for (int r = 0; r < 4; ++r) {
      float inv = lp[m][r];
      size_t rowoff = (size_t)(obase + r) * 9216;
#pragma unroll
      for (int n = 0; n < 6; ++n)
        ob[rowoff + n * 16 + l15] = oacc[m][n][r] * inv;
    }
  }
}

// ---------------------------------------------------------------------------
extern "C" void kernel_launch(void* const* d_in, const int* in_sizes, int n_in,
                              void* d_out, int out_size, void* d_ws, size_t ws_size,
                              hipStream_t stream) {
  const float* x  = (const float*)d_in[0];
  const float* y  = (const float*)d_in[1];
  const float* wy = (const float*)d_in[2];
  const float* by = (const float*)d_in[3];
  const float* wq = (const float*)d_in[4];
  const float* bq = (const float*)d_in[5];
  const float* wk = (const float*)d_in[6];
  const float* bk = (const float*)d_in[7];
  const float* wv = (const float*)d_in[8];
  const float* bv = (const float*)d_in[9];
  float* out = (float*)d_out;

  char* wsb = (char*)d_ws;
  bf16* wq_bf = (bf16*)(wsb);
  bf16* wk_bf = (bf16*)(wsb + 131072);
  bf16* wv_bf = (bf16*)(wsb + 262144);
  float* yu   = (float*)(wsb + 393216);
  float* aq   = (float*)(wsb + 688128);
  float* cq   = (float*)(wsb + 689152);
  float* ak   = (float*)(wsb + 690176);
  float* ck   = (float*)(wsb + 691200);
  const size_t fixed = 692224;
  const size_t per_bh = 3 * 24576 * 2;   // q,k,v bf16 per (b,h) pair

  // chunk over batch so any reasonable ws_size works (>= ~115 MB -> 1 chunk)
  size_t avail = ws_size > fixed ? ws_size - fixed : 0;
  long cap = (long)(avail / per_bh);
  int nb = (int)(cap / 96);
  if (nb > 8) nb = 8;
  if (nb < 1) nb = 1;
  int chunk_pairs = nb * 96;

  bf16* q_g = (bf16*)(wsb + fixed);
  bf16* k_g = q_g + (size_t)chunk_pairs * 24576;
  bf16* v_t = k_g + (size_t)chunk_pairs * 24576;

  hipLaunchKernelGGL(k_prep, dim3(232), dim3(256), 0, stream,
                     y, wy, by, wq, bq, wk, bk, wv,
                     wq_bf, wk_bf, wv_bf, yu, aq, cq, ak, ck);
  for (int b0 = 0; b0 < 8; b0 += nb) {
    int nbc = nb; if (b0 + nbc > 8) nbc = 8 - b0;
    int pairs = nbc * 96;
    hipLaunchKernelGGL(k_proj, dim3(pairs), dim3(256), 0, stream,
                       x, yu, wq_bf, wk_bf, wv_bf, bq, bk, bv,
                       aq, cq, ak, ck, q_g, k_g, v_t, b0 * 96);
    hipLaunchKernelGGL(k_attn, dim3(pairs), dim3(256), 0, stream,
                       q_g, k_g, v_t, out, b0 * 96);
  }
}

// Round 3
// 293.558 us; speedup vs baseline: 1.2060x; 1.1306x over previous
//
#include <hip/hip_runtime.h>

typedef __bf16 bf16;
typedef __attribute__((ext_vector_type(8))) __bf16 bf16x8;
typedef __attribute__((ext_vector_type(4))) __bf16 bf16x4;
typedef __attribute__((ext_vector_type(4))) float f32x4;

#define MFMA16(A, B, C) __builtin_amdgcn_mfma_f32_16x16x32_bf16(A, B, C, 0, 0, 0)

static __device__ __forceinline__ void wave_lgkm_wait() {
  asm volatile("s_waitcnt lgkmcnt(0)" ::: "memory");
}

// ---------------------------------------------------------------------------
// k_prep: weight bf16 conversion, yu bilinear upsample, gating coefficients
// grid = 232 blocks x 256
// ---------------------------------------------------------------------------
__global__ __launch_bounds__(256) void k_prep(
    const float* __restrict__ y, const float* __restrict__ wy, const float* __restrict__ by,
    const float* __restrict__ wq, const float* __restrict__ bq,
    const float* __restrict__ wk, const float* __restrict__ bk,
    const float* __restrict__ wv,
    bf16* __restrict__ wq_bf, bf16* __restrict__ wk_bf, bf16* __restrict__ wv_bf,
    float* __restrict__ yu, float* __restrict__ aq, float* __restrict__ cq,
    float* __restrict__ ak, float* __restrict__ ck)
{
  int blk = blockIdx.x, t = threadIdx.x;
  if (blk < 192) {
    int idx4 = blk * 256 + t;
    int fo = idx4 * 4;
    const float* src; bf16* dst; int off;
    if (fo < 65536)       { src = wq; dst = wq_bf; off = fo; }
    else if (fo < 131072) { src = wk; dst = wk_bf; off = fo - 65536; }
    else                  { src = wv; dst = wv_bf; off = fo - 131072; }
    float4 v = *(const float4*)(src + off);
    bf16x4 o;
    o[0] = (bf16)v.x; o[1] = (bf16)v.y; o[2] = (bf16)v.z; o[3] = (bf16)v.w;
    *(bf16x4*)(dst + off) = o;
  } else if (blk < 200) {
    // bilinear upsample y[b,1,24,24] -> yu[b,96,96], half-pixel, edge clamp
    int b = blk - 192;
    const float* yb = y + b * 576;
#pragma unroll 1
    for (int i = 0; i < 36; ++i) {
      int e = t + i * 256;
      int oh = e / 96, ow = e % 96;
      float sh = oh * 0.25f - 0.375f;
      float sw = ow * 0.25f - 0.375f;
      int ih0 = (int)floorf(sh);
      int iw0 = (int)floorf(sw);
      float fh = sh - (float)ih0, fw = sw - (float)iw0;
      int ih0c = min(23, max(0, ih0)), ih1c = min(23, max(0, ih0 + 1));
      int iw0c = min(23, max(0, iw0)), iw1c = min(23, max(0, iw0 + 1));
      float v00 = yb[ih0c * 24 + iw0c], v01 = yb[ih0c * 24 + iw1c];
      float v10 = yb[ih1c * 24 + iw0c], v11 = yb[ih1c * 24 + iw1c];
      yu[b * 9216 + e] = (1.0f - fh) * ((1.0f - fw) * v00 + fw * v01)
                       + fh * ((1.0f - fw) * v10 + fw * v11);
    }
  } else {
    // gate coefficients: aq = wq*wy, cq = wq*by + bq (same for k)
    int ol = t >> 5, cl = t & 31;
    int o = (blk - 200) * 8 + ol;
    int c0 = cl * 8;
    float4 wy0 = *(const float4*)(wy + c0), wy1 = *(const float4*)(wy + c0 + 4);
    float4 by0 = *(const float4*)(by + c0), by1 = *(const float4*)(by + c0 + 4);
    float4 q0  = *(const float4*)(wq + o * 256 + c0), q1 = *(const float4*)(wq + o * 256 + c0 + 4);
    float4 k0  = *(const float4*)(wk + o * 256 + c0), k1 = *(const float4*)(wk + o * 256 + c0 + 4);
    float wyv[8] = {wy0.x, wy0.y, wy0.z, wy0.w, wy1.x, wy1.y, wy1.z, wy1.w};
    float byv[8] = {by0.x, by0.y, by0.z, by0.w, by1.x, by1.y, by1.z, by1.w};
    float qv[8]  = {q0.x, q0.y, q0.z, q0.w, q1.x, q1.y, q1.z, q1.w};
    float kv[8]  = {k0.x, k0.y, k0.z, k0.w, k1.x, k1.y, k1.z, k1.w};
    float saq = 0.f, scq = 0.f, sak = 0.f, sck = 0.f;
#pragma unroll
    for (int j = 0; j < 8; ++j) {
      saq += qv[j] * wyv[j]; scq += qv[j] * byv[j];
      sak += kv[j] * wyv[j]; sck += kv[j] * byv[j];
    }
#pragma unroll
    for (int s = 16; s >= 1; s >>= 1) {
      saq += __shfl_xor(saq, s, 32);
      scq += __shfl_xor(scq, s, 32);
      sak += __shfl_xor(sak, s, 32);
      sck += __shfl_xor(sck, s, 32);
    }
    if (cl == 0) {
      aq[o] = saq; cq[o] = scq + bq[o];
      ak[o] = sak; ck[o] = sck + bk[o];
    }
  }
}

// ---------------------------------------------------------------------------
// k_fused: one block per (b,h) row. Projections (q->regs, k->LDS, v->LDS
// reusing xs) then channel attention, all on-chip. No q/k/v HBM round-trip.
//   LDS: xs [96 w][264 c]   50688 B  (reused as vs [96 w][264 d] after proj)
//        ks [256 d][104 w]  53248 B
//        bounce 4x[64][40]  20480 B  (per-wave; doubles as q transpose stage)
//   Total 124416 B -> 1 block/CU (gfx950 has 160 KiB LDS).
// ---------------------------------------------------------------------------
__global__ __launch_bounds__(256, 1) void k_fused(
    const float* __restrict__ x, const float* __restrict__ yu,
    const bf16* __restrict__ wq_bf, const bf16* __restrict__ wk_bf, const bf16* __restrict__ wv_bf,
    const float* __restrict__ bq, const float* __restrict__ bk, const float* __restrict__ bv,
    const float* __restrict__ aq, const float* __restrict__ cq,
    const float* __restrict__ ak, const float* __restrict__ ck,
    float* __restrict__ out)
{
  __shared__ __align__(16) bf16 xs[96 * 264];          // 50688 B (-> vs)
  __shared__ __align__(16) bf16 ks[256 * 104];         // 53248 B
  __shared__ __align__(16) bf16 bounce[4 * 64 * 40];   // 20480 B

  int pl = blockIdx.x;
  int b = pl / 96, h = pl % 96;
  int t = threadIdx.x;
  int wid = t >> 6, lane = t & 63;
  int l15 = lane & 15, g = lane >> 4;

  // ---- phase 0: load x[b,:,h,:] -> xs[w][c] (bf16) ----
  {
    const float* xrow = x + (size_t)b * 2359296 + (size_t)h * 96;
#pragma unroll 2
    for (int i = 0; i < 12; ++i) {
      int tsk = i * 256 + t;        // 96 w x 32 cgroups
      int w = tsk % 96;
      int c0 = (tsk / 96) * 8;
      float v[8];
#pragma unroll
      for (int j = 0; j < 8; ++j) v[j] = xrow[(size_t)(c0 + j) * 9216 + w];
      bf16x8 o8;
#pragma unroll
      for (int j = 0; j < 8; ++j) o8[j] = (bf16)v[j];
      *(bf16x8*)(xs + w * 264 + c0) = o8;
    }
  }
  __syncthreads();

  // yu gate values for this row, w = mt*16 + g*4 + r
  float4 yv[6];
  {
    const float* yr = yu + (size_t)pl * 96;
#pragma unroll
    for (int mt = 0; mt < 6; ++mt)
      yv[mt] = *(const float4*)(yr + mt * 16 + g * 4);
  }

  bf16* stg = bounce + wid * (64 * 40);   // per-wave stage, 16x104 fits in 64x40
  const float SC = 0.17677669529663687f;  // 1/sqrt(32), folded into q

  bf16x8 qf[4][3];   // this wave's 64 o-rows of q, A-fragment layout

  // ---- phase 1: q projection (swapped D[m=w][n=o]), gate, -> qf registers ----
  {
    f32x4 acc[6][4] = {};
#pragma unroll 1
    for (int kq = 0; kq < 8; ++kq) {
      bf16x8 A[6];
      const bf16* xp = xs + kq * 32 + g * 8;
#pragma unroll
      for (int m = 0; m < 6; ++m)
        A[m] = *(const bf16x8*)(xp + (m * 16 + l15) * 264);
      const bf16* wp = wq_bf + (size_t)(wid * 64 + l15) * 256 + kq * 32 + g * 8;
#pragma unroll
      for (int n = 0; n < 4; ++n) {
        bf16x8 B = *(const bf16x8*)(wp + n * 16 * 256);
#pragma unroll
        for (int m = 0; m < 6; ++m)
          acc[m][n] = MFMA16(A[m], B, acc[m][n]);
      }
    }
#pragma unroll 1
    for (int n = 0; n < 4; ++n) {
      int o = wid * 64 + n * 16 + l15;
      float biasv = bq[o], a0 = aq[o], c0 = cq[o];
#pragma unroll
      for (int m = 0; m < 6; ++m) {
        float yy[4] = {yv[m].x, yv[m].y, yv[m].z, yv[m].w};
        bf16x4 pk;
#pragma unroll
        for (int r = 0; r < 4; ++r)
          pk[r] = (bf16)((acc[m][n][r] + biasv) * (yy[r] * a0 + c0) * SC);
        *(bf16x4*)(stg + l15 * 104 + m * 16 + g * 4) = pk;
      }
      wave_lgkm_wait();
#pragma unroll
      for (int kk = 0; kk < 3; ++kk)
        qf[n][kk] = *(const bf16x8*)(stg + l15 * 104 + kk * 32 + g * 8);
      wave_lgkm_wait();   // reads retired before next stripe overwrites
    }
  }

  // ---- phase 2: k projection, gate, -> ks[d][w] LDS ----
  {
    f32x4 acc[6][4] = {};
#pragma unroll 1
    for (int kq = 0; kq < 8; ++kq) {
      bf16x8 A[6];
      const bf16* xp = xs + kq * 32 + g * 8;
#pragma unroll
      for (int m = 0; m < 6; ++m)
        A[m] = *(const bf16x8*)(xp + (m * 16 + l15) * 264);
      const bf16* wp = wk_bf + (size_t)(wid * 64 + l15) * 256 + kq * 32 + g * 8;
#pragma unroll
      for (int n = 0; n < 4; ++n) {
        bf16x8 B = *(const bf16x8*)(wp + n * 16 * 256);
#pragma unroll
        for (int m = 0; m < 6; ++m)
          acc[m][n] = MFMA16(A[m], B, acc[m][n]);
      }
    }
#pragma unroll 1
    for (int n = 0; n < 4; ++n) {
      int o = wid * 64 + n * 16 + l15;
      float biasv = bk[o], a0 = ak[o], c0 = ck[o];
#pragma unroll
      for (int m = 0; m < 6; ++m) {
        float yy[4] = {yv[m].x, yv[m].y, yv[m].z, yv[m].w};
        bf16x4 pk;
#pragma unroll
        for (int r = 0; r < 4; ++r)
          pk[r] = (bf16)((acc[m][n][r] + biasv) * (yy[r] * a0 + c0));
        *(bf16x4*)(ks + (size_t)o * 104 + m * 16 + g * 4) = pk;
      }
    }
  }

  // ---- phase 3: v projection (natural D[m=d][n=w]) -> regs, then vs=xs ----
  {
    f32x4 acc[4][6] = {};
#pragma unroll 1
    for (int kq = 0; kq < 8; ++kq) {
      bf16x8 A[4];
      const bf16* wp = wv_bf + (size_t)(wid * 64 + l15) * 256 + kq * 32 + g * 8;
#pragma unroll
      for (int m = 0; m < 4; ++m)
        A[m] = *(const bf16x8*)(wp + m * 16 * 256);
      const bf16* xp = xs + kq * 32 + g * 8;
#pragma unroll
      for (int n = 0; n < 6; ++n) {
        bf16x8 B = *(const bf16x8*)(xp + (n * 16 + l15) * 264);
#pragma unroll
        for (int m = 0; m < 4; ++m)
          acc[m][n] = MFMA16(A[m], B, acc[m][n]);
      }
    }
    float bb[4][4];
#pragma unroll
    for (int m = 0; m < 4; ++m) {
      float4 bm = *(const float4*)(bv + wid * 64 + m * 16 + g * 4);
      bb[m][0] = bm.x; bb[m][1] = bm.y; bb[m][2] = bm.z; bb[m][3] = bm.w;
    }
    __syncthreads();   // ALL waves done reading xs (and ks writes done)
    bf16* vs = xs;     // reuse xs as vs[w][264 d]
#pragma unroll
    for (int m = 0; m < 4; ++m) {
      int d0 = wid * 64 + m * 16 + g * 4;
#pragma unroll
      for (int n = 0; n < 6; ++n) {
        bf16x4 pk;
#pragma unroll
        for (int r = 0; r < 4; ++r) pk[r] = (bf16)(acc[m][n][r] + bb[m][r]);
        *(bf16x4*)(vs + (size_t)(n * 16 + l15) * 264 + d0) = pk;
      }
    }
  }
  __syncthreads();     // ks + vs visible to all waves

  // ---- phase 4: attention. scores (q pre-scaled), exp, bounce, out=P*v ----
  const bf16* vs = xs;
  f32x4 oacc[4][6] = {};
  float lp[4][4];
#pragma unroll
  for (int m = 0; m < 4; ++m)
#pragma unroll
    for (int r = 0; r < 4; ++r) lp[m][r] = 0.0f;

  bf16* bnc = bounce + wid * (64 * 40);

#pragma unroll 1
  for (int dt = 0; dt < 8; ++dt) {
    int d0 = dt * 32;
    f32x4 s[4][2] = {};
    const bf16* kp = ks + (size_t)(d0 + l15) * 104 + g * 8;
#pragma unroll
    for (int kk = 0; kk < 3; ++kk) {
#pragma unroll
      for (int dn = 0; dn < 2; ++dn) {
        bf16x8 B = *(const bf16x8*)(kp + (size_t)dn * 16 * 104 + kk * 32);
#pragma unroll
        for (int m = 0; m < 4; ++m)
          s[m][dn] = MFMA16(qf[m][kk], B, s[m][dn]);
      }
    }
#pragma unroll
    for (int m = 0; m < 4; ++m) {
#pragma unroll
      for (int dn = 0; dn < 2; ++dn) {
#pragma unroll
        for (int r = 0; r < 4; ++r) {
          float e = __expf(s[m][dn][r]);
          lp[m][r] += e;
          bnc[(m * 16 + g * 4 + r) * 40 + dn * 16 + l15] = (bf16)e;
        }
      }
    }
    wave_lgkm_wait();
    bf16x8 pa[4];
#pragma unroll
    for (int m = 0; m < 4; ++m)
      pa[m] = *(const bf16x8*)(bnc + (m * 16 + l15) * 40 + g * 8);
    const bf16* vp = vs + (size_t)l15 * 264 + d0 + g * 8;
#pragma unroll
    for (int n = 0; n < 6; ++n) {
      bf16x8 Bv = *(const bf16x8*)(vp + (size_t)n * 16 * 264);
#pragma unroll
      for (int m = 0; m < 4; ++m)
        oacc[m][n] = MFMA16(pa[m], Bv, oacc[m][n]);
    }
    wave_lgkm_wait();   // pa retired before next-iter bounce writes (WAR)
  }

  // row-sum reduce across the 4 lane-groups holding the same rows
#pragma unroll
  for (int m = 0; m < 4; ++m)
#pragma unroll
    for (int r = 0; r < 4; ++r) {
      float v = lp[m][r];
      v += __shfl_xor(v, 1, 16);
      v += __shfl_xor(v, 2, 16);
      v += __shfl_xor(v, 4, 16);
      v += __shfl_xor(v, 8, 16);
      lp[m][r] = 1.0f / v;
    }

  // epilogue: out[b, o, h, w] = oacc / rowsum (4x 64B full-line stores/inst)
  float* ob = out + (size_t)b * 2359296 + (size_t)h * 96;
#pragma unroll
  for (int m = 0; m < 4; ++m) {
    int obase = wid * 64 + m * 16 + g * 4;
#pragma unroll
    for (int r = 0; r < 4; ++r) {
      float inv = lp[m][r];
      size_t rowoff = (size_t)(obase + r) * 9216;
#pragma unroll
      for (int n = 0; n < 6; ++n)
        ob[rowoff + n * 16 + l15] = oacc[m][n][r] * inv;
    }
  }
}

// ---------------------------------------------------------------------------
extern "C" void kernel_launch(void* const* d_in, const int* in_sizes, int n_in,
                              void* d_out, int out_size, void* d_ws, size_t ws_size,
                              hipStream_t stream) {
  const float* x  = (const float*)d_in[0];
  const float* y  = (const float*)d_in[1];
  const float* wy = (const float*)d_in[2];
  const float* by = (const float*)d_in[3];
  const float* wq = (const float*)d_in[4];
  const float* bq = (const float*)d_in[5];
  const float* wk = (const float*)d_in[6];
  const float* bk = (const float*)d_in[7];
  const float* wv = (const float*)d_in[8];
  const float* bv = (const float*)d_in[9];
  float* out = (float*)d_out;

  char* wsb = (char*)d_ws;
  bf16* wq_bf = (bf16*)(wsb);
  bf16* wk_bf = (bf16*)(wsb + 131072);
  bf16* wv_bf = (bf16*)(wsb + 262144);
  float* yu   = (float*)(wsb + 393216);
  float* aq   = (float*)(wsb + 688128);
  float* cq   = (float*)(wsb + 689152);
  float* ak   = (float*)(wsb + 690176);
  float* ck   = (float*)(wsb + 691200);

  hipLaunchKernelGGL(k_prep, dim3(232), dim3(256), 0, stream,
                     y, wy, by, wq, bq, wk, bk, wv,
                     wq_bf, wk_bf, wv_bf, yu, aq, cq, ak, ck);
  hipLaunchKernelGGL(k_fused, dim3(768), dim3(256), 0, stream,
                     x, yu, wq_bf, wk_bf, wv_bf, bq, bk, bv,
                     aq, cq, ak, ck, out);
}

// Round 4
// 222.582 us; speedup vs baseline: 1.5905x; 1.3189x over previous
//
#include <hip/hip_runtime.h>

typedef __bf16 bf16;
typedef __attribute__((ext_vector_type(8))) __bf16 bf16x8;
typedef __attribute__((ext_vector_type(4))) __bf16 bf16x4;
typedef __attribute__((ext_vector_type(4))) float f32x4;

#define MFMA16(A, B, C) __builtin_amdgcn_mfma_f32_16x16x32_bf16(A, B, C, 0, 0, 0)

static __device__ __forceinline__ void wave_lgkm_wait() {
  asm volatile("s_waitcnt lgkmcnt(0)" ::: "memory");
}

// ---------------------------------------------------------------------------
// k_prep: weight bf16 conversion, yu bilinear upsample, gating coefficients
// grid = 232 blocks x 256
// ---------------------------------------------------------------------------
__global__ __launch_bounds__(256) void k_prep(
    const float* __restrict__ y, const float* __restrict__ wy, const float* __restrict__ by,
    const float* __restrict__ wq, const float* __restrict__ bq,
    const float* __restrict__ wk, const float* __restrict__ bk,
    const float* __restrict__ wv,
    bf16* __restrict__ wq_bf, bf16* __restrict__ wk_bf, bf16* __restrict__ wv_bf,
    float* __restrict__ yu, float* __restrict__ aq, float* __restrict__ cq,
    float* __restrict__ ak, float* __restrict__ ck)
{
  int blk = blockIdx.x, t = threadIdx.x;
  if (blk < 192) {
    int idx4 = blk * 256 + t;
    int fo = idx4 * 4;
    const float* src; bf16* dst; int off;
    if (fo < 65536)       { src = wq; dst = wq_bf; off = fo; }
    else if (fo < 131072) { src = wk; dst = wk_bf; off = fo - 65536; }
    else                  { src = wv; dst = wv_bf; off = fo - 131072; }
    float4 v = *(const float4*)(src + off);
    bf16x4 o;
    o[0] = (bf16)v.x; o[1] = (bf16)v.y; o[2] = (bf16)v.z; o[3] = (bf16)v.w;
    *(bf16x4*)(dst + off) = o;
  } else if (blk < 200) {
    // bilinear upsample y[b,1,24,24] -> yu[b,96,96], half-pixel, edge clamp
    int b = blk - 192;
    const float* yb = y + b * 576;
#pragma unroll 1
    for (int i = 0; i < 36; ++i) {
      int e = t + i * 256;
      int oh = e / 96, ow = e % 96;
      float sh = oh * 0.25f - 0.375f;
      float sw = ow * 0.25f - 0.375f;
      int ih0 = (int)floorf(sh);
      int iw0 = (int)floorf(sw);
      float fh = sh - (float)ih0, fw = sw - (float)iw0;
      int ih0c = min(23, max(0, ih0)), ih1c = min(23, max(0, ih0 + 1));
      int iw0c = min(23, max(0, iw0)), iw1c = min(23, max(0, iw0 + 1));
      float v00 = yb[ih0c * 24 + iw0c], v01 = yb[ih0c * 24 + iw1c];
      float v10 = yb[ih1c * 24 + iw0c], v11 = yb[ih1c * 24 + iw1c];
      yu[b * 9216 + e] = (1.0f - fh) * ((1.0f - fw) * v00 + fw * v01)
                       + fh * ((1.0f - fw) * v10 + fw * v11);
    }
  } else {
    // gate coefficients: aq = wq*wy, cq = wq*by + bq (same for k)
    int ol = t >> 5, cl = t & 31;
    int o = (blk - 200) * 8 + ol;
    int c0 = cl * 8;
    float4 wy0 = *(const float4*)(wy + c0), wy1 = *(const float4*)(wy + c0 + 4);
    float4 by0 = *(const float4*)(by + c0), by1 = *(const float4*)(by + c0 + 4);
    float4 q0  = *(const float4*)(wq + o * 256 + c0), q1 = *(const float4*)(wq + o * 256 + c0 + 4);
    float4 k0  = *(const float4*)(wk + o * 256 + c0), k1 = *(const float4*)(wk + o * 256 + c0 + 4);
    float wyv[8] = {wy0.x, wy0.y, wy0.z, wy0.w, wy1.x, wy1.y, wy1.z, wy1.w};
    float byv[8] = {by0.x, by0.y, by0.z, by0.w, by1.x, by1.y, by1.z, by1.w};
    float qv[8]  = {q0.x, q0.y, q0.z, q0.w, q1.x, q1.y, q1.z, q1.w};
    float kv[8]  = {k0.x, k0.y, k0.z, k0.w, k1.x, k1.y, k1.z, k1.w};
    float saq = 0.f, scq = 0.f, sak = 0.f, sck = 0.f;
#pragma unroll
    for (int j = 0; j < 8; ++j) {
      saq += qv[j] * wyv[j]; scq += qv[j] * byv[j];
      sak += kv[j] * wyv[j]; sck += kv[j] * byv[j];
    }
#pragma unroll
    for (int s = 16; s >= 1; s >>= 1) {
      saq += __shfl_xor(saq, s, 32);
      scq += __shfl_xor(scq, s, 32);
      sak += __shfl_xor(sak, s, 32);
      sck += __shfl_xor(sck, s, 32);
    }
    if (cl == 0) {
      aq[o] = saq; cq[o] = scq + bq[o];
      ak[o] = sak; ck[o] = sck + bk[o];
    }
  }
}

// ---------------------------------------------------------------------------
// k_fused: one block of 1024 threads (16 waves, 4/SIMD) per (b,h) row.
// Each wave owns one 16-row o/d tile. All intermediates on-chip.
//   LDS: xs [96 w][264 c]   50688 B  (reused as vs [96 w][264 d] after proj)
//        ks [256 o][104 w]  53248 B  (per-wave q-stage aliases its own region;
//                                     reused as f32 out-stage [128][100] at end)
//        bounce 16x[16][40] 20480 B
//   Total 124416 B -> 1 block/CU, 16 waves = 4 waves/SIMD.
// ---------------------------------------------------------------------------
__global__ __launch_bounds__(1024, 1) void k_fused(
    const float* __restrict__ x, const float* __restrict__ yu,
    const bf16* __restrict__ wq_bf, const bf16* __restrict__ wk_bf, const bf16* __restrict__ wv_bf,
    const float* __restrict__ bq, const float* __restrict__ bk, const float* __restrict__ bv,
    const float* __restrict__ aq, const float* __restrict__ cq,
    const float* __restrict__ ak, const float* __restrict__ ck,
    float* __restrict__ out)
{
  __shared__ __align__(16) bf16 xs[96 * 264];          // 50688 B (-> vs)
  __shared__ __align__(16) bf16 ks[256 * 104];         // 53248 B (-> out stage)
  __shared__ __align__(16) bf16 bounce[16 * 16 * 40];  // 20480 B

  int pl = blockIdx.x;
  int b = pl / 96, h = pl % 96;
  int t = threadIdx.x;
  int wid = t >> 6, lane = t & 63;
  int l15 = lane & 15, g = lane >> 4;
  int otile = wid * 16;            // this wave's 16-row o/d tile base

  // ---- phase 0: load x[b,:,h,:] -> xs[w][c] (bf16) ----
  {
    const float* xrow = x + (size_t)b * 2359296 + (size_t)h * 96;
#pragma unroll
    for (int i = 0; i < 3; ++i) {
      int tsk = i * 1024 + t;       // 96 w x 32 cgroups
      int w = tsk % 96;
      int c0 = (tsk / 96) * 8;
      float v[8];
#pragma unroll
      for (int j = 0; j < 8; ++j) v[j] = xrow[(size_t)(c0 + j) * 9216 + w];
      bf16x8 o8;
#pragma unroll
      for (int j = 0; j < 8; ++j) o8[j] = (bf16)v[j];
      *(bf16x8*)(xs + w * 264 + c0) = o8;
    }
  }
  __syncthreads();

  // yu gate values for this row, w = mt*16 + g*4 + r
  float4 yv[6];
  {
    const float* yr = yu + (size_t)pl * 96;
#pragma unroll
    for (int mt = 0; mt < 6; ++mt)
      yv[mt] = *(const float4*)(yr + mt * 16 + g * 4);
  }

  const float SC = 0.17677669529663687f;  // 1/sqrt(32), folded into q
  bf16* stg = ks + otile * 104;           // q-stage aliases this wave's k region

  bf16x8 qf[3];   // this wave's 16 o-rows of q, A-fragment layout

  // ---- phase 1: q projection (swapped D[m=w][n=o tile]), gate -> qf regs ----
  {
    f32x4 acc[6] = {};
#pragma unroll 1
    for (int kq = 0; kq < 8; ++kq) {
      bf16x8 A[6];
      const bf16* xp = xs + kq * 32 + g * 8;
#pragma unroll
      for (int m = 0; m < 6; ++m)
        A[m] = *(const bf16x8*)(xp + (m * 16 + l15) * 264);
      bf16x8 B = *(const bf16x8*)(wq_bf + (size_t)(otile + l15) * 256 + kq * 32 + g * 8);
#pragma unroll
      for (int m = 0; m < 6; ++m)
        acc[m] = MFMA16(A[m], B, acc[m]);
    }
    int o = otile + l15;
    float biasv = bq[o], a0 = aq[o], c0 = cq[o];
#pragma unroll
    for (int m = 0; m < 6; ++m) {
      float yy[4] = {yv[m].x, yv[m].y, yv[m].z, yv[m].w};
      bf16x4 pk;
#pragma unroll
      for (int r = 0; r < 4; ++r)
        pk[r] = (bf16)((acc[m][r] + biasv) * (yy[r] * a0 + c0) * SC);
      *(bf16x4*)(stg + l15 * 104 + m * 16 + g * 4) = pk;
    }
    wave_lgkm_wait();
#pragma unroll
    for (int kk = 0; kk < 3; ++kk)
      qf[kk] = *(const bf16x8*)(stg + l15 * 104 + kk * 32 + g * 8);
    wave_lgkm_wait();   // reads landed before phase 2 overwrites this region
  }

  // ---- phase 2: k projection, gate -> ks[o][w] (this wave's 16 rows) ----
  {
    f32x4 acc[6] = {};
#pragma unroll 1
    for (int kq = 0; kq < 8; ++kq) {
      bf16x8 A[6];
      const bf16* xp = xs + kq * 32 + g * 8;
#pragma unroll
      for (int m = 0; m < 6; ++m)
        A[m] = *(const bf16x8*)(xp + (m * 16 + l15) * 264);
      bf16x8 B = *(const bf16x8*)(wk_bf + (size_t)(otile + l15) * 256 + kq * 32 + g * 8);
#pragma unroll
      for (int m = 0; m < 6; ++m)
        acc[m] = MFMA16(A[m], B, acc[m]);
    }
    int o = otile + l15;
    float biasv = bk[o], a0 = ak[o], c0 = ck[o];
#pragma unroll
    for (int m = 0; m < 6; ++m) {
      float yy[4] = {yv[m].x, yv[m].y, yv[m].z, yv[m].w};
      bf16x4 pk;
#pragma unroll
      for (int r = 0; r < 4; ++r)
        pk[r] = (bf16)((acc[m][r] + biasv) * (yy[r] * a0 + c0));
      *(bf16x4*)(ks + (size_t)o * 104 + m * 16 + g * 4) = pk;
    }
  }

  // ---- phase 3: v projection (natural D[m=d tile][n=w]) -> regs, vs = xs ----
  {
    f32x4 acc[6] = {};
#pragma unroll 1
    for (int kq = 0; kq < 8; ++kq) {
      bf16x8 A = *(const bf16x8*)(wv_bf + (size_t)(otile + l15) * 256 + kq * 32 + g * 8);
      const bf16* xp = xs + kq * 32 + g * 8;
#pragma unroll
      for (int n = 0; n < 6; ++n) {
        bf16x8 B = *(const bf16x8*)(xp + (n * 16 + l15) * 264);
        acc[n] = MFMA16(A, B, acc[n]);
      }
    }
    float4 bm = *(const float4*)(bv + otile + g * 4);
    float bb[4] = {bm.x, bm.y, bm.z, bm.w};
    __syncthreads();   // ALL waves done reading xs (and q-stage/k writes local)
    bf16* vs = xs;     // reuse xs as vs[w][264 d]
#pragma unroll
    for (int n = 0; n < 6; ++n) {
      bf16x4 pk;
#pragma unroll
      for (int r = 0; r < 4; ++r) pk[r] = (bf16)(acc[n][r] + bb[r]);
      *(bf16x4*)(vs + (size_t)(n * 16 + l15) * 264 + otile + g * 4) = pk;
    }
  }
  __syncthreads();     // ks + vs visible to all waves

  // ---- phase 4: scores (q pre-scaled), exp, bounce, out = P*v ----
  const bf16* vs = xs;
  f32x4 oacc[6] = {};
  float lp[4] = {0.f, 0.f, 0.f, 0.f};
  bf16* bnc = bounce + wid * (16 * 40);

#pragma unroll 1
  for (int dt = 0; dt < 8; ++dt) {
    int d0 = dt * 32;
    f32x4 s[2] = {};
    const bf16* kp = ks + (size_t)(d0 + l15) * 104 + g * 8;
#pragma unroll
    for (int kk = 0; kk < 3; ++kk) {
#pragma unroll
      for (int dn = 0; dn < 2; ++dn) {
        bf16x8 B = *(const bf16x8*)(kp + (size_t)dn * 16 * 104 + kk * 32);
        s[dn] = MFMA16(qf[kk], B, s[dn]);
      }
    }
#pragma unroll
    for (int dn = 0; dn < 2; ++dn) {
#pragma unroll
      for (int r = 0; r < 4; ++r) {
        float e = __expf(s[dn][r]);
        lp[r] += e;
        bnc[(g * 4 + r) * 40 + dn * 16 + l15] = (bf16)e;
      }
    }
    wave_lgkm_wait();
    bf16x8 pa = *(const bf16x8*)(bnc + l15 * 40 + g * 8);
    const bf16* vp = vs + (size_t)l15 * 264 + d0 + g * 8;
#pragma unroll
    for (int n = 0; n < 6; ++n) {
      bf16x8 Bv = *(const bf16x8*)(vp + (size_t)n * 16 * 264);
      oacc[n] = MFMA16(pa, Bv, oacc[n]);
    }
    wave_lgkm_wait();   // pa retired before next-iter bounce writes (WAR)
  }

  // row-sum reduce across the 16 l15 lanes holding the same rows
  float inv[4];
#pragma unroll
  for (int r = 0; r < 4; ++r) {
    float v = lp[r];
    v += __shfl_xor(v, 1, 16);
    v += __shfl_xor(v, 2, 16);
    v += __shfl_xor(v, 4, 16);
    v += __shfl_xor(v, 8, 16);
    inv[r] = 1.0f / v;
  }

  // ---- epilogue: stage f32 rows in LDS (ks reuse), flush full 384B rows ----
  __syncthreads();                  // everyone done reading ks
  float* fst = (float*)ks;          // [128 rows][pitch 100] = 51200 B
  int s_hi = wid >> 3;
  int lr = (wid & 7) * 16;
  float* ob = out + (size_t)b * 2359296 + (size_t)h * 96;
#pragma unroll 1
  for (int s = 0; s < 2; ++s) {
    if (s_hi == s) {
#pragma unroll
      for (int n = 0; n < 6; ++n)
#pragma unroll
        for (int r = 0; r < 4; ++r)
          fst[(lr + g * 4 + r) * 100 + n * 16 + l15] = oacc[n][r] * inv[r];
    }
    __syncthreads();
    int ob0 = s * 128;
#pragma unroll
    for (int it = 0; it < 3; ++it) {
      int idx = it * 1024 + t;      // 0..3071 float4 chunks
      int row = idx / 24, col = idx - row * 24;
      float4 v4 = *(const float4*)(fst + row * 100 + col * 4);
      *(float4*)(ob + (size_t)(ob0 + row) * 9216 + col * 4) = v4;
    }
    __syncthreads();
  }
}

// ---------------------------------------------------------------------------
extern "C" void kernel_launch(void* const* d_in, const int* in_sizes, int n_in,
                              void* d_out, int out_size, void* d_ws, size_t ws_size,
                              hipStream_t stream) {
  const float* x  = (const float*)d_in[0];
  const float* y  = (const float*)d_in[1];
  const float* wy = (const float*)d_in[2];
  const float* by = (const float*)d_in[3];
  const float* wq = (const float*)d_in[4];
  const float* bq = (const float*)d_in[5];
  const float* wk = (const float*)d_in[6];
  const float* bk = (const float*)d_in[7];
  const float* wv = (const float*)d_in[8];
  const float* bv = (const float*)d_in[9];
  float* out = (float*)d_out;

  char* wsb = (char*)d_ws;
  bf16* wq_bf = (bf16*)(wsb);
  bf16* wk_bf = (bf16*)(wsb + 131072);
  bf16* wv_bf = (bf16*)(wsb + 262144);
  float* yu   = (float*)(wsb + 393216);
  float* aq   = (float*)(wsb + 688128);
  float* cq   = (float*)(wsb + 689152);
  float* ak   = (float*)(wsb + 690176);
  float* ck   = (float*)(wsb + 691200);

  hipLaunchKernelGGL(k_prep, dim3(232), dim3(256), 0, stream,
                     y, wy, by, wq, bq, wk, bk, wv,
                     wq_bf, wk_bf, wv_bf, yu, aq, cq, ak, ck);
  hipLaunchKernelGGL(k_fused, dim3(768), dim3(1024), 0, stream,
                     x, yu, wq_bf, wk_bf, wv_bf, bq, bk, bv,
                     aq, cq, ak, ck, out);
}